// Round 7
// baseline (178.414 us; speedup 1.0000x reference)
//
#include <hip/hip_runtime.h>

#define B_DIM 8
#define M_MICS 8
#define F_DIM 257
#define T_DIM 2000
#define NPROB (B_DIM * F_DIM)   // 2056
#define TILE 256
#define NFULL 7                  // 7*256 = 1792; tail = 208
#define TAILW 208

// Per-problem MVDR weights, written by K1, read by K2 (deterministic, graph-safe).
__device__ float g_w[NPROB * 16];

#define GLOAD_LDS(g, s) __builtin_amdgcn_global_load_lds(                       \
    (const __attribute__((address_space(1))) void*)(g),                         \
    (__attribute__((address_space(3))) void*)(s), 16, 0, 0)

// LDS tile rows: [0..7]=re mic m, [8..15]=im mic m, [16]=smask, [17]=nmask.
// Pair q enumeration (m<n): q0-3:(0,1)(0,2)(0,3)(0,4) q4-7:(0,5)(0,6)(0,7)(1,2)
// q8-11:(1,3)(1,4)(1,5)(1,6) q12-15:(1,7)(2,3)(2,4)(2,5) q16-19:(2,6)(2,7)(3,4)(3,5)
// q20-23:(3,6)(3,7)(4,5)(4,6) q24-27:(4,7)(5,6)(5,7)(6,7)
// wave0 = msums+diags (18 acc); wave w(1..7) = pairs q in [4w-4,4w),
// acc[4*(q&3)+t], t:0=ss_re 1=ss_im 2=nn_re 3=nn_im.
// Solve reads: diag -> sG[0][2+m]/sG[0][10+m]; pair q -> sG[1+(q>>2)][4*(q&3)+t].

#define PAIR_ACC(a, bb, k)                                              \
    {                                                                   \
        const float pr = yr[a][u] * yr[bb][u] + yi[a][u] * yi[bb][u];   \
        const float pi = yi[a][u] * yr[bb][u] - yr[a][u] * yi[bb][u];   \
        acc[(k) + 0] += msv[u] * pr;                                    \
        acc[(k) + 1] += msv[u] * pi;                                    \
        acc[(k) + 2] += mnv[u] * pr;                                    \
        acc[(k) + 3] += mnv[u] * pi;                                    \
    }

#define LOADM(k, mic)                                                             \
    {                                                                             \
        const float4 vr_ = *reinterpret_cast<const float4*>(&lds[bb][mic][4 * l]);      \
        const float4 vi_ = *reinterpret_cast<const float4*>(&lds[bb][8 + (mic)][4 * l]);\
        yr[k][0] = vr_.x; yr[k][1] = vr_.y; yr[k][2] = vr_.z; yr[k][3] = vr_.w;   \
        yi[k][0] = vi_.x; yi[k][1] = vi_.y; yi[k][2] = vi_.z; yi[k][3] = vi_.w;   \
    }

#define PAIR_BODY(LOADS, ACCS, KM)                                      \
    {                                                                   \
        float yr[KM][4], yi[KM][4];                                     \
        LOADS                                                           \
        _Pragma("unroll")                                               \
        for (int u = 0; u < 4; ++u) { ACCS }                            \
    }

// ==================== K1: LDS-staged covariance + solve ======================
__launch_bounds__(512, 4)
__global__ void cov_solve_kernel(const float* __restrict__ sre, const float* __restrict__ sim,
                                 const float* __restrict__ smask, const float* __restrict__ nmask)
{
    const int f = blockIdx.x, b = blockIdx.y, tid = threadIdx.x;
    const int h = tid >> 6, l = tid & 63;   // wave id (0..7), lane

    __shared__ float lds[2][18][TILE];
    __shared__ float sG[8][20];

    const size_t mrow = (size_t)F_DIM * T_DIM;
    const size_t base_bf = ((size_t)(b * M_MICS) * F_DIM + f) * T_DIM;
    const size_t mbase   = ((size_t)b * F_DIM + f) * T_DIM;

    // wave h stages mic-h re/im rows; waves 0/1 also stage the mask rows
    const float* g_re = sre + base_bf + (size_t)h * mrow;
    const float* g_im = sim + base_bf + (size_t)h * mrow;
    const float* g_ms = smask + mbase;
    const float* g_mn = nmask + mbase;

    float acc[18];
#pragma unroll
    for (int i = 0; i < 18; ++i) acc[i] = 0.f;

    auto STAGE = [&](int bb, int toff, int tw) {
        if (4 * l < tw) {
            GLOAD_LDS(g_re + toff + 4 * l, &lds[bb][h][0]);
            GLOAD_LDS(g_im + toff + 4 * l, &lds[bb][8 + h][0]);
            if (h == 0)      GLOAD_LDS(g_ms + toff + 4 * l, &lds[bb][16][0]);
            else if (h == 1) GLOAD_LDS(g_mn + toff + 4 * l, &lds[bb][17][0]);
        }
    };

    auto COMPUTE = [&](int bb) {
        float msv[4], mnv[4];
        {
            const float4 v = *reinterpret_cast<const float4*>(&lds[bb][16][4 * l]);
            msv[0] = v.x; msv[1] = v.y; msv[2] = v.z; msv[3] = v.w;
        }
        {
            const float4 v = *reinterpret_cast<const float4*>(&lds[bb][17][4 * l]);
            mnv[0] = v.x; mnv[1] = v.y; mnv[2] = v.z; mnv[3] = v.w;
        }
        if (h == 0) {
            acc[0] += msv[0] + msv[1] + msv[2] + msv[3];
            acc[1] += mnv[0] + mnv[1] + mnv[2] + mnv[3];
#pragma unroll
            for (int m = 0; m < 8; ++m) {
                const float4 re4 = *reinterpret_cast<const float4*>(&lds[bb][m][4 * l]);
                const float4 im4 = *reinterpret_cast<const float4*>(&lds[bb][8 + m][4 * l]);
                const float rr[4] = { re4.x, re4.y, re4.z, re4.w };
                const float ii[4] = { im4.x, im4.y, im4.z, im4.w };
#pragma unroll
                for (int u = 0; u < 4; ++u) {
                    const float pd = rr[u] * rr[u] + ii[u] * ii[u];
                    acc[2 + m]  += msv[u] * pd;
                    acc[10 + m] += mnv[u] * pd;
                }
            }
        } else if (h == 1) {
            // mics {0,1,2,3,4}; pairs (0,1)(0,2)(0,3)(0,4)
            PAIR_BODY(LOADM(0,0) LOADM(1,1) LOADM(2,2) LOADM(3,3) LOADM(4,4),
                      PAIR_ACC(0,1,0) PAIR_ACC(0,2,4) PAIR_ACC(0,3,8) PAIR_ACC(0,4,12), 5)
        } else if (h == 2) {
            // mics {0,1,2,5,6,7}->0..5; pairs (0,5)(0,6)(0,7)(1,2)
            PAIR_BODY(LOADM(0,0) LOADM(1,1) LOADM(2,2) LOADM(3,5) LOADM(4,6) LOADM(5,7),
                      PAIR_ACC(0,3,0) PAIR_ACC(0,4,4) PAIR_ACC(0,5,8) PAIR_ACC(1,2,12), 6)
        } else if (h == 3) {
            // mics {1,3,4,5,6}->0..4; pairs (1,3)(1,4)(1,5)(1,6)
            PAIR_BODY(LOADM(0,1) LOADM(1,3) LOADM(2,4) LOADM(3,5) LOADM(4,6),
                      PAIR_ACC(0,1,0) PAIR_ACC(0,2,4) PAIR_ACC(0,3,8) PAIR_ACC(0,4,12), 5)
        } else if (h == 4) {
            // mics {1,2,3,4,5,7}->0..5; pairs (1,7)(2,3)(2,4)(2,5)
            PAIR_BODY(LOADM(0,1) LOADM(1,2) LOADM(2,3) LOADM(3,4) LOADM(4,5) LOADM(5,7),
                      PAIR_ACC(0,5,0) PAIR_ACC(1,2,4) PAIR_ACC(1,3,8) PAIR_ACC(1,4,12), 6)
        } else if (h == 5) {
            // mics {2,3,4,5,6,7}->0..5; pairs (2,6)(2,7)(3,4)(3,5)
            PAIR_BODY(LOADM(0,2) LOADM(1,3) LOADM(2,4) LOADM(3,5) LOADM(4,6) LOADM(5,7),
                      PAIR_ACC(0,4,0) PAIR_ACC(0,5,4) PAIR_ACC(1,2,8) PAIR_ACC(1,3,12), 6)
        } else if (h == 6) {
            // mics {3,4,5,6,7}->0..4; pairs (3,6)(3,7)(4,5)(4,6)
            PAIR_BODY(LOADM(0,3) LOADM(1,4) LOADM(2,5) LOADM(3,6) LOADM(4,7),
                      PAIR_ACC(0,3,0) PAIR_ACC(0,4,4) PAIR_ACC(1,2,8) PAIR_ACC(1,3,12), 5)
        } else {
            // mics {4,5,6,7}->0..3; pairs (4,7)(5,6)(5,7)(6,7)
            PAIR_BODY(LOADM(0,4) LOADM(1,5) LOADM(2,6) LOADM(3,7),
                      PAIR_ACC(0,3,0) PAIR_ACC(1,2,4) PAIR_ACC(1,3,8) PAIR_ACC(2,3,12), 4)
        }
    };

    // -------- pipelined loop: stage tile t+1 while computing tile t -----------
    STAGE(0, 0, TILE);
    __syncthreads();                 // drains vmcnt -> tile 0 resident
#pragma unroll 1
    for (int t = 0; t < NFULL; ++t) {
        if (t < NFULL - 1) STAGE((t + 1) & 1, (t + 1) * TILE, TILE);
        else               STAGE(1, NFULL * TILE, TAILW);
        const int bb = t & 1;
        COMPUTE(bb);                 // full tile: all 64 lanes
        __syncthreads();             // reads done + next tile staged
    }
    if (4 * l < TAILW) {             // tail tile (208 samples) from buf 1
        const int bb = 1;
        COMPUTE(bb);
    }

    // ----- per-wave butterfly reduction, lane 0 -> LDS ------------------------
#pragma unroll
    for (int i = 0; i < 18; ++i) {
        acc[i] += __shfl_xor(acc[i], 1, 64);
        acc[i] += __shfl_xor(acc[i], 2, 64);
        acc[i] += __shfl_xor(acc[i], 4, 64);
        acc[i] += __shfl_xor(acc[i], 8, 64);
        acc[i] += __shfl_xor(acc[i], 16, 64);
        acc[i] += __shfl_xor(acc[i], 32, 64);
    }
    if (l == 0) {
#pragma unroll
        for (int i = 0; i < 18; ++i) sG[h][i] = acc[i];
    }
    __syncthreads();

    // ----- solve: wave 0 only, lane = (r, c) of the 8x8 (verbatim from r6) ----
    if (tid < 64) {
        const int r = tid >> 3, cc = tid & 7;
        const float Ssum = sG[0][0] + 1e-8f;
        const float Nsum = sG[0][1] + 1e-8f;

        float ssr, ssi, ar, ai;
        if (r == cc) {
            ssr = sG[0][2 + r] / Ssum;  ssi = 0.f;
            ar  = sG[0][10 + r] / Nsum + 1e-5f;  ai = 0.f;
        } else {
            const int mm  = (r < cc) ? r : cc;
            const int nn2 = (r < cc) ? cc : r;
            const int q = mm * 8 - mm * (mm + 1) / 2 + nn2 - mm - 1;
            const int g = 1 + (q >> 2);
            const int basei = 4 * (q & 3);
            const float sgn = (r < cc) ? 1.f : -1.f;
            ssr = sG[g][basei] / Ssum;
            ssi = sgn * sG[g][basei + 1] / Ssum;
            ar  = sG[g][basei + 2] / Nsum;
            ai  = sgn * sG[g][basei + 3] / Nsum;
        }

        // Gauss-Jordan inverse of Phi_nn (Hermitian PD)
        float br = (r == cc) ? 1.f : 0.f, bi = 0.f;
        for (int k = 0; k < 8; ++k) {
            const float pr = __shfl(ar, k * 9, 64);
            const float pi = __shfl(ai, k * 9, 64);
            const float den = pr * pr + pi * pi;
            const float qr = pr / den, qi = -pi / den;
            const bool isk = (r == k);
            const float ar2 = ar * qr - ai * qi;
            const float ai2 = ar * qi + ai * qr;
            const float br2 = br * qr - bi * qi;
            const float bi2 = br * qi + bi * qr;
            ar = isk ? ar2 : ar; ai = isk ? ai2 : ai;
            br = isk ? br2 : br; bi = isk ? bi2 : bi;
            const float rar = __shfl(ar, k * 8 + cc, 64);
            const float rai = __shfl(ai, k * 8 + cc, 64);
            const float rbr = __shfl(br, k * 8 + cc, 64);
            const float rbi = __shfl(bi, k * 8 + cc, 64);
            const float fr = __shfl(ar, r * 8 + k, 64);
            const float fi = __shfl(ai, r * 8 + k, 64);
            const float uar = ar - (fr * rar - fi * rai);
            const float uai = ai - (fr * rai + fi * rar);
            const float ubr = br - (fr * rbr - fi * rbi);
            const float ubi = bi - (fr * rbi + fi * rbr);
            ar = isk ? ar : uar; ai = isk ? ai : uai;
            br = isk ? br : ubr; bi = isk ? bi : ubi;
        }

        // G = Phi_nn_inv @ Phi_ss
        float gr = 0.f, gi = 0.f;
        for (int k = 0; k < 8; ++k) {
            const float ir = __shfl(br, r * 8 + k, 64);
            const float ii = __shfl(bi, r * 8 + k, 64);
            const float skr = __shfl(ssr, k * 8 + cc, 64);
            const float ski = __shfl(ssi, k * 8 + cc, 64);
            gr += ir * skr - ii * ski;
            gi += ir * ski + ii * skr;
        }

        // power iteration (30 iters)
        float vr = 1.f, vi = 0.f;
        for (int itp = 0; itp < 30; ++itp) {
            float wr2 = gr * vr - gi * vi;
            float wi2 = gr * vi + gi * vr;
            wr2 += __shfl_xor(wr2, 1, 64); wi2 += __shfl_xor(wi2, 1, 64);
            wr2 += __shfl_xor(wr2, 2, 64); wi2 += __shfl_xor(wi2, 2, 64);
            wr2 += __shfl_xor(wr2, 4, 64); wi2 += __shfl_xor(wi2, 4, 64);
            float nrm = wr2 * wr2 + wi2 * wi2;
            nrm += __shfl_xor(nrm, 8, 64);
            nrm += __shfl_xor(nrm, 16, 64);
            nrm += __shfl_xor(nrm, 32, 64);
            const float inv = 1.f / (sqrtf(nrm) + 1e-12f);
            wr2 *= inv; wi2 *= inv;
            vr = __shfl(wr2, cc * 9, 64);
            vi = __shfl(wi2, cc * 9, 64);
        }

        // rtf = v / (v[0] + 1e-8)
        const float v0r = __shfl(vr, 0, 64) + 1e-8f;
        const float v0i = __shfl(vi, 0, 64);
        const float dd = v0r * v0r + v0i * v0i;
        const float rtr = (vr * v0r + vi * v0i) / dd;
        const float rti = (vi * v0r - vr * v0i) / dd;

        // d = Phi_nn_inv @ rtf
        float dr = br * rtr - bi * rti;
        float di = br * rti + bi * rtr;
        dr += __shfl_xor(dr, 1, 64); di += __shfl_xor(di, 1, 64);
        dr += __shfl_xor(dr, 2, 64); di += __shfl_xor(di, 2, 64);
        dr += __shfl_xor(dr, 4, 64); di += __shfl_xor(di, 4, 64);

        float qden = (r == cc) ? (rtr * dr + rti * di) : 0.f;
        qden += __shfl_xor(qden, 1, 64); qden += __shfl_xor(qden, 2, 64);
        qden += __shfl_xor(qden, 4, 64); qden += __shfl_xor(qden, 8, 64);
        qden += __shfl_xor(qden, 16, 64); qden += __shfl_xor(qden, 32, 64);
        qden += 1e-8f;

        if (cc == 0) {
            const int p = b * F_DIM + f;
            g_w[p * 16 + r]     = dr / qden;
            g_w[p * 16 + 8 + r] = di / qden;
        }
    }
}

// ============================ K2: apply (pure streaming, proven) =============
__launch_bounds__(256, 8)
__global__ void apply_kernel(const float* __restrict__ sre, const float* __restrict__ sim,
                             float* __restrict__ out, int out_mode)
{
    const int f = blockIdx.x, b = blockIdx.y, z = blockIdx.z;
    const int tid = threadIdx.x;
    __shared__ float sW[16];
    const int p = b * F_DIM + f;
    if (tid < 16) sW[tid] = g_w[p * 16 + tid];
    __syncthreads();

    const int t0 = z * 512 + 2 * tid;
    if (t0 >= T_DIM) return;

    const size_t mrow = (size_t)F_DIM * T_DIM;
    const size_t base_bf = ((size_t)(b * M_MICS) * F_DIM + f) * T_DIM;
    const size_t mbase   = ((size_t)b * F_DIM + f) * T_DIM;

    float er0 = 0.f, ei0 = 0.f, er1 = 0.f, ei1 = 0.f;
#pragma unroll
    for (int m = 0; m < 8; ++m) {
        const float2 vr2 = *reinterpret_cast<const float2*>(sre + base_bf + (size_t)m * mrow + t0);
        const float2 vi2 = *reinterpret_cast<const float2*>(sim + base_bf + (size_t)m * mrow + t0);
        const float wr = sW[m], wi = sW[8 + m];
        er0 += wr * vr2.x + wi * vi2.x;
        ei0 += wr * vi2.x - wi * vr2.x;
        er1 += wr * vr2.y + wi * vi2.y;
        ei1 += wr * vi2.y - wi * vr2.y;
    }
    if (out_mode == 2) {
        *reinterpret_cast<float4*>(out + 2 * (mbase + t0)) = make_float4(er0, ei0, er1, ei1);
    } else {
        *reinterpret_cast<float2*>(out + mbase + t0) = make_float2(er0, er1);
    }
}

extern "C" void kernel_launch(void* const* d_in, const int* in_sizes, int n_in,
                              void* d_out, int out_size, void* d_ws, size_t ws_size,
                              hipStream_t stream)
{
    const float* sre   = (const float*)d_in[0];
    const float* sim   = (const float*)d_in[1];
    const float* smask = (const float*)d_in[2];
    const float* nmask = (const float*)d_in[3];
    float* out = (float*)d_out;

    const int mode = (out_size >= 2 * B_DIM * F_DIM * T_DIM) ? 2 : 1;

    cov_solve_kernel<<<dim3(F_DIM, B_DIM), 512, 0, stream>>>(sre, sim, smask, nmask);
    apply_kernel<<<dim3(F_DIM, B_DIM, 4), 256, 0, stream>>>(sre, sim, out, mode);
}

// Round 9
// 161.256 us; speedup vs baseline: 1.1064x; 1.1064x over previous
//
#include <hip/hip_runtime.h>

#define B_DIM 8
#define M_MICS 8
#define F_DIM 257
#define T_DIM 2000
#define NPROB (B_DIM * F_DIM)   // 2056
#define TILE 256
#define CHUNK 1000               // 2 chunks per problem
#define NTILE 4                  // 3*256 + 232
#define TAILW 232

// Device-global intermediates (deterministic every call; no d_ws dependence).
// Partial covariance layout PL[144] per (problem, chunk):
// [0]=msum_s [1]=msum_n [2..9]=ss_diag m0..7 [10..17]=nn_diag m0..7
// [18+4q+t] for pair q=0..27, t: 0=ss_re 1=ss_im 2=nn_re 3=nn_im
__device__ float g_cov[NPROB * 2 * 144];
__device__ float g_w[NPROB * 16];

#define GLOAD_LDS(g, s) __builtin_amdgcn_global_load_lds(                       \
    (const __attribute__((address_space(1))) void*)(g),                         \
    (__attribute__((address_space(3))) void*)(s), 16, 0, 0)

// q(m,n) = m*8 - m(m+1)/2 + n - m - 1:
// (0,1)=0 (0,2)=1 (0,3)=2 (0,4)=3 (0,5)=4 (0,6)=5 (0,7)=6
// (1,2)=7 (1,3)=8 (1,4)=9 (1,5)=10 (1,6)=11 (1,7)=12
// (2,3)=13 (2,4)=14 (2,5)=15 (2,6)=16 (2,7)=17
// (3,4)=18 (3,5)=19 (3,6)=20 (3,7)=21 (4,5)=22 (4,6)=23 (4,7)=24
// (5,6)=25 (5,7)=26 (6,7)=27
// Wave->work groups (each reads <=4 mics + masks => 10 LDS rows/tile):
//  h0: msums + ss/nn diag mics 0-3          h7: ss/nn diag mics 4-7
//  h1: K4{0,1,2,3}: q 0,1,2,7,8,13          h2: K4{4,5,6,7}: q 22..27
//  h3: {0,1}x{4,5}: q 3,4,9,10              h4: {0,1}x{6,7}: q 5,6,11,12
//  h5: {2,3}x{4,5}: q 14,15,18,19           h6: {2,3}x{6,7}: q 16,17,20,21
// NOTE (r8 bug): q-row stride shrinks with m; the {q0,q0+1,q0+6,q0+7} formula
// was wrong for h5/h6 -> explicit per-group q lists below.

#define PAIR_ACC(a, bb2, k)                                             \
    {                                                                   \
        const float pr = yr[a][u] * yr[bb2][u] + yi[a][u] * yi[bb2][u]; \
        const float pi = yi[a][u] * yr[bb2][u] - yr[a][u] * yi[bb2][u]; \
        acc[(k) + 0] += msv[u] * pr;                                    \
        acc[(k) + 1] += msv[u] * pi;                                    \
        acc[(k) + 2] += mnv[u] * pr;                                    \
        acc[(k) + 3] += mnv[u] * pi;                                    \
    }

#define LOADM(k, mic)                                                                   \
    {                                                                                   \
        const float4 vr_ = *reinterpret_cast<const float4*>(&lds[bb][mic][4 * l]);      \
        const float4 vi_ = *reinterpret_cast<const float4*>(&lds[bb][8 + (mic)][4 * l]);\
        yr[k][0] = vr_.x; yr[k][1] = vr_.y; yr[k][2] = vr_.z; yr[k][3] = vr_.w;         \
        yi[k][0] = vi_.x; yi[k][1] = vi_.y; yi[k][2] = vi_.z; yi[k][3] = vi_.w;         \
    }

#define MASKS4                                                                   \
    float msv[4], mnv[4];                                                        \
    {                                                                            \
        const float4 v = *reinterpret_cast<const float4*>(&lds[bb][16][4 * l]);  \
        msv[0] = v.x; msv[1] = v.y; msv[2] = v.z; msv[3] = v.w;                  \
        const float4 w = *reinterpret_cast<const float4*>(&lds[bb][17][4 * l]);  \
        mnv[0] = w.x; mnv[1] = w.y; mnv[2] = w.z; mnv[3] = w.w;                  \
    }

// =========================== K1: covariance partials =========================
__launch_bounds__(512, 4)
__global__ void cov_kernel(const float* __restrict__ sre, const float* __restrict__ sim,
                           const float* __restrict__ smask, const float* __restrict__ nmask)
{
    const int f = blockIdx.x, b = blockIdx.y, c = blockIdx.z;
    const int tid = threadIdx.x;
    const int h = tid >> 6, l = tid & 63;

    __shared__ float lds[2][18][TILE];

    const size_t mrow = (size_t)F_DIM * T_DIM;
    const size_t base_bf = ((size_t)(b * M_MICS) * F_DIM + f) * T_DIM + (size_t)c * CHUNK;
    const size_t mbase   = ((size_t)b * F_DIM + f) * T_DIM + (size_t)c * CHUNK;

    const float* g_re = sre + base_bf + (size_t)h * mrow;
    const float* g_im = sim + base_bf + (size_t)h * mrow;
    const float* g_ms = smask + mbase;
    const float* g_mn = nmask + mbase;

    float acc[24];
#pragma unroll
    for (int i = 0; i < 24; ++i) acc[i] = 0.f;

    auto STAGE = [&](int bb, int toff, int tw) {
        if (4 * l < tw) {
            GLOAD_LDS(g_re + toff + 4 * l, &lds[bb][h][0]);
            GLOAD_LDS(g_im + toff + 4 * l, &lds[bb][8 + h][0]);
            if (h == 0)      GLOAD_LDS(g_ms + toff + 4 * l, &lds[bb][16][0]);
            else if (h == 1) GLOAD_LDS(g_mn + toff + 4 * l, &lds[bb][17][0]);
        }
    };

    auto COMPUTE = [&](int bb, int tw) {
        if (4 * l >= tw) return;
        MASKS4
        if (h == 0) {
            acc[0] += msv[0] + msv[1] + msv[2] + msv[3];
            acc[1] += mnv[0] + mnv[1] + mnv[2] + mnv[3];
#pragma unroll
            for (int j = 0; j < 4; ++j) {
                const float4 re4 = *reinterpret_cast<const float4*>(&lds[bb][j][4 * l]);
                const float4 im4 = *reinterpret_cast<const float4*>(&lds[bb][8 + j][4 * l]);
                const float rr[4] = { re4.x, re4.y, re4.z, re4.w };
                const float ii[4] = { im4.x, im4.y, im4.z, im4.w };
#pragma unroll
                for (int u = 0; u < 4; ++u) {
                    const float pd = rr[u] * rr[u] + ii[u] * ii[u];
                    acc[2 + j] += msv[u] * pd;
                    acc[6 + j] += mnv[u] * pd;
                }
            }
        } else if (h == 7) {
#pragma unroll
            for (int j = 0; j < 4; ++j) {
                const float4 re4 = *reinterpret_cast<const float4*>(&lds[bb][4 + j][4 * l]);
                const float4 im4 = *reinterpret_cast<const float4*>(&lds[bb][12 + j][4 * l]);
                const float rr[4] = { re4.x, re4.y, re4.z, re4.w };
                const float ii[4] = { im4.x, im4.y, im4.z, im4.w };
#pragma unroll
                for (int u = 0; u < 4; ++u) {
                    const float pd = rr[u] * rr[u] + ii[u] * ii[u];
                    acc[j]     += msv[u] * pd;
                    acc[4 + j] += mnv[u] * pd;
                }
            }
        } else if (h == 1) {
            float yr[4][4], yi[4][4];
            LOADM(0,0) LOADM(1,1) LOADM(2,2) LOADM(3,3)
#pragma unroll
            for (int u = 0; u < 4; ++u) {
                PAIR_ACC(0,1,0) PAIR_ACC(0,2,4) PAIR_ACC(0,3,8)
                PAIR_ACC(1,2,12) PAIR_ACC(1,3,16) PAIR_ACC(2,3,20)
            }
        } else if (h == 2) {
            float yr[4][4], yi[4][4];
            LOADM(0,4) LOADM(1,5) LOADM(2,6) LOADM(3,7)
#pragma unroll
            for (int u = 0; u < 4; ++u) {
                PAIR_ACC(0,1,0) PAIR_ACC(0,2,4) PAIR_ACC(0,3,8)
                PAIR_ACC(1,2,12) PAIR_ACC(1,3,16) PAIR_ACC(2,3,20)
            }
        } else if (h == 3) {
            float yr[4][4], yi[4][4];
            LOADM(0,0) LOADM(1,1) LOADM(2,4) LOADM(3,5)
#pragma unroll
            for (int u = 0; u < 4; ++u) {
                PAIR_ACC(0,2,0) PAIR_ACC(0,3,4) PAIR_ACC(1,2,8) PAIR_ACC(1,3,12)
            }
        } else if (h == 4) {
            float yr[4][4], yi[4][4];
            LOADM(0,0) LOADM(1,1) LOADM(2,6) LOADM(3,7)
#pragma unroll
            for (int u = 0; u < 4; ++u) {
                PAIR_ACC(0,2,0) PAIR_ACC(0,3,4) PAIR_ACC(1,2,8) PAIR_ACC(1,3,12)
            }
        } else if (h == 5) {
            float yr[4][4], yi[4][4];
            LOADM(0,2) LOADM(1,3) LOADM(2,4) LOADM(3,5)
#pragma unroll
            for (int u = 0; u < 4; ++u) {
                PAIR_ACC(0,2,0) PAIR_ACC(0,3,4) PAIR_ACC(1,2,8) PAIR_ACC(1,3,12)
            }
        } else {
            float yr[4][4], yi[4][4];
            LOADM(0,2) LOADM(1,3) LOADM(2,6) LOADM(3,7)
#pragma unroll
            for (int u = 0; u < 4; ++u) {
                PAIR_ACC(0,2,0) PAIR_ACC(0,3,4) PAIR_ACC(1,2,8) PAIR_ACC(1,3,12)
            }
        }
    };

    // pipelined: stage t+1 while computing t
    STAGE(0, 0, TILE);
    __syncthreads();
#pragma unroll 1
    for (int t = 0; t < NTILE; ++t) {
        const int tw = (t == NTILE - 1) ? TAILW : TILE;
        if (t < NTILE - 1) STAGE((t + 1) & 1, (t + 1) * TILE, (t + 1 == NTILE - 1) ? TAILW : TILE);
        COMPUTE(t & 1, tw);
        __syncthreads();
    }

    // per-wave butterfly reduction
#pragma unroll
    for (int i = 0; i < 24; ++i) {
        acc[i] += __shfl_xor(acc[i], 1, 64);
        acc[i] += __shfl_xor(acc[i], 2, 64);
        acc[i] += __shfl_xor(acc[i], 4, 64);
        acc[i] += __shfl_xor(acc[i], 8, 64);
        acc[i] += __shfl_xor(acc[i], 16, 64);
        acc[i] += __shfl_xor(acc[i], 32, 64);
    }

    if (l == 0) {
        const int p = b * F_DIM + f;
        float* dst = g_cov + ((size_t)p * 2 + c) * 144;
        if (h == 0) {
            dst[0] = acc[0]; dst[1] = acc[1];
#pragma unroll
            for (int j = 0; j < 4; ++j) { dst[2 + j] = acc[2 + j]; dst[10 + j] = acc[6 + j]; }
        } else if (h == 7) {
#pragma unroll
            for (int j = 0; j < 4; ++j) { dst[6 + j] = acc[j]; dst[14 + j] = acc[4 + j]; }
        } else if (h == 1) {
            const int qs[6] = {0, 1, 2, 7, 8, 13};
#pragma unroll
            for (int i = 0; i < 6; ++i)
#pragma unroll
                for (int t2 = 0; t2 < 4; ++t2) dst[18 + 4 * qs[i] + t2] = acc[4 * i + t2];
        } else if (h == 2) {
            const int qs[6] = {22, 23, 24, 25, 26, 27};
#pragma unroll
            for (int i = 0; i < 6; ++i)
#pragma unroll
                for (int t2 = 0; t2 < 4; ++t2) dst[18 + 4 * qs[i] + t2] = acc[4 * i + t2];
        } else if (h == 3) {
            const int qs[4] = {3, 4, 9, 10};      // (0,4)(0,5)(1,4)(1,5)
#pragma unroll
            for (int i = 0; i < 4; ++i)
#pragma unroll
                for (int t2 = 0; t2 < 4; ++t2) dst[18 + 4 * qs[i] + t2] = acc[4 * i + t2];
        } else if (h == 4) {
            const int qs[4] = {5, 6, 11, 12};     // (0,6)(0,7)(1,6)(1,7)
#pragma unroll
            for (int i = 0; i < 4; ++i)
#pragma unroll
                for (int t2 = 0; t2 < 4; ++t2) dst[18 + 4 * qs[i] + t2] = acc[4 * i + t2];
        } else if (h == 5) {
            const int qs[4] = {14, 15, 18, 19};   // (2,4)(2,5)(3,4)(3,5)
#pragma unroll
            for (int i = 0; i < 4; ++i)
#pragma unroll
                for (int t2 = 0; t2 < 4; ++t2) dst[18 + 4 * qs[i] + t2] = acc[4 * i + t2];
        } else {
            const int qs[4] = {16, 17, 20, 21};   // (2,6)(2,7)(3,6)(3,7)
#pragma unroll
            for (int i = 0; i < 4; ++i)
#pragma unroll
                for (int t2 = 0; t2 < 4; ++t2) dst[18 + 4 * qs[i] + t2] = acc[4 * i + t2];
        }
    }
}

// ============================ K2: solve (all problems concurrent) ============
__launch_bounds__(256, 4)
__global__ void solve_kernel()
{
    const int tid = threadIdx.x;
    const int w = tid >> 6, lane = tid & 63;
    const int p = blockIdx.x * 4 + w;

    __shared__ float sPhi[4][144];
    {
        const float* s0 = g_cov + (size_t)p * 2 * 144;
        for (int i = lane; i < 144; i += 64) sPhi[w][i] = s0[i] + s0[144 + i];
    }
    __syncthreads();

    const int r = lane >> 3, cc = lane & 7;
    const float Ssum = sPhi[w][0] + 1e-8f;
    const float Nsum = sPhi[w][1] + 1e-8f;

    float ssr, ssi, ar, ai;
    if (r == cc) {
        ssr = sPhi[w][2 + r] / Ssum;  ssi = 0.f;
        ar  = sPhi[w][10 + r] / Nsum + 1e-5f;  ai = 0.f;
    } else {
        const int mm  = (r < cc) ? r : cc;
        const int nn2 = (r < cc) ? cc : r;
        const int q = mm * 8 - mm * (mm + 1) / 2 + nn2 - mm - 1;
        const int basei = 18 + 4 * q;
        const float sgn = (r < cc) ? 1.f : -1.f;
        ssr = sPhi[w][basei] / Ssum;
        ssi = sgn * sPhi[w][basei + 1] / Ssum;
        ar  = sPhi[w][basei + 2] / Nsum;
        ai  = sgn * sPhi[w][basei + 3] / Nsum;
    }

    // Gauss-Jordan inverse of Phi_nn (Hermitian PD)
    float br = (r == cc) ? 1.f : 0.f, bi = 0.f;
    for (int k = 0; k < 8; ++k) {
        const float pr = __shfl(ar, k * 9, 64);
        const float pi = __shfl(ai, k * 9, 64);
        const float den = pr * pr + pi * pi;
        const float qr = pr / den, qi = -pi / den;
        const bool isk = (r == k);
        const float ar2 = ar * qr - ai * qi;
        const float ai2 = ar * qi + ai * qr;
        const float br2 = br * qr - bi * qi;
        const float bi2 = br * qi + bi * qr;
        ar = isk ? ar2 : ar; ai = isk ? ai2 : ai;
        br = isk ? br2 : br; bi = isk ? bi2 : bi;
        const float rar = __shfl(ar, k * 8 + cc, 64);
        const float rai = __shfl(ai, k * 8 + cc, 64);
        const float rbr = __shfl(br, k * 8 + cc, 64);
        const float rbi = __shfl(bi, k * 8 + cc, 64);
        const float fr = __shfl(ar, r * 8 + k, 64);
        const float fi = __shfl(ai, r * 8 + k, 64);
        const float uar = ar - (fr * rar - fi * rai);
        const float uai = ai - (fr * rai + fi * rar);
        const float ubr = br - (fr * rbr - fi * rbi);
        const float ubi = bi - (fr * rbi + fi * rbr);
        ar = isk ? ar : uar; ai = isk ? ai : uai;
        br = isk ? br : ubr; bi = isk ? bi : ubi;
    }

    // G = Phi_nn_inv @ Phi_ss
    float gr = 0.f, gi = 0.f;
    for (int k = 0; k < 8; ++k) {
        const float ir = __shfl(br, r * 8 + k, 64);
        const float ii = __shfl(bi, r * 8 + k, 64);
        const float skr = __shfl(ssr, k * 8 + cc, 64);
        const float ski = __shfl(ssi, k * 8 + cc, 64);
        gr += ir * skr - ii * ski;
        gi += ir * ski + ii * skr;
    }

    // power iteration (30 iters)
    float vr = 1.f, vi = 0.f;
    for (int itp = 0; itp < 30; ++itp) {
        float wr2 = gr * vr - gi * vi;
        float wi2 = gr * vi + gi * vr;
        wr2 += __shfl_xor(wr2, 1, 64); wi2 += __shfl_xor(wi2, 1, 64);
        wr2 += __shfl_xor(wr2, 2, 64); wi2 += __shfl_xor(wi2, 2, 64);
        wr2 += __shfl_xor(wr2, 4, 64); wi2 += __shfl_xor(wi2, 4, 64);
        float nrm = wr2 * wr2 + wi2 * wi2;
        nrm += __shfl_xor(nrm, 8, 64);
        nrm += __shfl_xor(nrm, 16, 64);
        nrm += __shfl_xor(nrm, 32, 64);
        const float inv = 1.f / (sqrtf(nrm) + 1e-12f);
        wr2 *= inv; wi2 *= inv;
        vr = __shfl(wr2, cc * 9, 64);
        vi = __shfl(wi2, cc * 9, 64);
    }

    // rtf = v / (v[0] + 1e-8)
    const float v0r = __shfl(vr, 0, 64) + 1e-8f;
    const float v0i = __shfl(vi, 0, 64);
    const float dd = v0r * v0r + v0i * v0i;
    const float rtr = (vr * v0r + vi * v0i) / dd;
    const float rti = (vi * v0r - vr * v0i) / dd;

    // d = Phi_nn_inv @ rtf
    float dr = br * rtr - bi * rti;
    float di = br * rti + bi * rtr;
    dr += __shfl_xor(dr, 1, 64); di += __shfl_xor(di, 1, 64);
    dr += __shfl_xor(dr, 2, 64); di += __shfl_xor(di, 2, 64);
    dr += __shfl_xor(dr, 4, 64); di += __shfl_xor(di, 4, 64);

    float qden = (r == cc) ? (rtr * dr + rti * di) : 0.f;
    qden += __shfl_xor(qden, 1, 64); qden += __shfl_xor(qden, 2, 64);
    qden += __shfl_xor(qden, 4, 64); qden += __shfl_xor(qden, 8, 64);
    qden += __shfl_xor(qden, 16, 64); qden += __shfl_xor(qden, 32, 64);
    qden += 1e-8f;

    if (cc == 0) {
        g_w[p * 16 + r]     = dr / qden;
        g_w[p * 16 + 8 + r] = di / qden;
    }
}

// ============================ K3: apply (pure streaming, proven) =============
__launch_bounds__(256, 8)
__global__ void apply_kernel(const float* __restrict__ sre, const float* __restrict__ sim,
                             float* __restrict__ out, int out_mode)
{
    const int f = blockIdx.x, b = blockIdx.y, z = blockIdx.z;
    const int tid = threadIdx.x;
    __shared__ float sW[16];
    const int p = b * F_DIM + f;
    if (tid < 16) sW[tid] = g_w[p * 16 + tid];
    __syncthreads();

    const int t0 = z * 512 + 2 * tid;
    if (t0 >= T_DIM) return;

    const size_t mrow = (size_t)F_DIM * T_DIM;
    const size_t base_bf = ((size_t)(b * M_MICS) * F_DIM + f) * T_DIM;
    const size_t mbase   = ((size_t)b * F_DIM + f) * T_DIM;

    float er0 = 0.f, ei0 = 0.f, er1 = 0.f, ei1 = 0.f;
#pragma unroll
    for (int m = 0; m < 8; ++m) {
        const float2 vr2 = *reinterpret_cast<const float2*>(sre + base_bf + (size_t)m * mrow + t0);
        const float2 vi2 = *reinterpret_cast<const float2*>(sim + base_bf + (size_t)m * mrow + t0);
        const float wr = sW[m], wi = sW[8 + m];
        er0 += wr * vr2.x + wi * vi2.x;
        ei0 += wr * vi2.x - wi * vr2.x;
        er1 += wr * vr2.y + wi * vi2.y;
        ei1 += wr * vi2.y - wi * vr2.y;
    }
    if (out_mode == 2) {
        *reinterpret_cast<float4*>(out + 2 * (mbase + t0)) = make_float4(er0, ei0, er1, ei1);
    } else {
        *reinterpret_cast<float2*>(out + mbase + t0) = make_float2(er0, er1);
    }
}

extern "C" void kernel_launch(void* const* d_in, const int* in_sizes, int n_in,
                              void* d_out, int out_size, void* d_ws, size_t ws_size,
                              hipStream_t stream)
{
    const float* sre   = (const float*)d_in[0];
    const float* sim   = (const float*)d_in[1];
    const float* smask = (const float*)d_in[2];
    const float* nmask = (const float*)d_in[3];
    float* out = (float*)d_out;

    const int mode = (out_size >= 2 * B_DIM * F_DIM * T_DIM) ? 2 : 1;

    cov_kernel<<<dim3(F_DIM, B_DIM, 2), 512, 0, stream>>>(sre, sim, smask, nmask);
    solve_kernel<<<dim3(NPROB / 4), 256, 0, stream>>>();
    apply_kernel<<<dim3(F_DIM, B_DIM, 4), 256, 0, stream>>>(sre, sim, out, mode);
}